// Round 11
// baseline (415.747 us; speedup 1.0000x reference)
//
#include <hip/hip_runtime.h>

#define N 8192
#define IN_F 512
#define OUT_F 128
#define SPLITK 8
#define KC 1024
#define LOG2E 1.4426950408889634f
#define LN2 0.6931471805599453f

typedef __attribute__((ext_vector_type(4))) float f32x4;
typedef __attribute__((ext_vector_type(8))) short bf16x8;
typedef __attribute__((ext_vector_type(8))) unsigned short u16x8;
typedef __attribute__((ext_vector_type(4))) int i32x4;

__device__ __forceinline__ short f2bf(float f) {
    union { float f; unsigned u; } c; c.f = f;
    unsigned r = c.u + 0x7FFFu + ((c.u >> 16) & 1u);
    return (short)(r >> 16);
}

__device__ __forceinline__ float exp2fast(float x) {
#if __has_builtin(__builtin_amdgcn_exp2f)
    return __builtin_amdgcn_exp2f(x);
#else
    return __expf(x * LN2);
#endif
}

__device__ __forceinline__ void load_lds16(const void* g, void* l) {
    __builtin_amdgcn_global_load_lds((const __attribute__((address_space(1))) unsigned*)g,
                                     (__attribute__((address_space(3))) unsigned*)l,
                                     16, 0, 0);
}

// ---------------------------------------------------------------- conv_W: W -> WT bf16 [OUT_F][IN_F]
__global__ __launch_bounds__(256) void conv_W(const float* __restrict__ W, short* __restrict__ WT) {
    int idx = blockIdx.x * 256 + threadIdx.x;
    int n = idx & (OUT_F - 1);
    int k = idx >> 7;
    WT[(size_t)n * IN_F + k] = f2bf(W[idx]);
}

// ---------------------------------------------------------------- gemm_hW: Wh=h@W -> WhT bf16 [OUT_F][N]; fused s,t (x LOG2E)
__global__ __launch_bounds__(256) void gemm_hW(const float* __restrict__ h,
                                               const short* __restrict__ WT,
                                               const float* __restrict__ a,
                                               short* __restrict__ WhT,
                                               float* __restrict__ sOut,
                                               float* __restrict__ tOut) {
    const int tid = threadIdx.x;
    const int wave = tid >> 6, lane = tid & 63;
    const int row16 = lane & 15, kgrp = lane >> 4;
    const int m0 = blockIdx.x * 16;
    const int kbase = wave * 128;

    f32x4 acc[8] = {};
    const float4* hp = (const float4*)(h + (size_t)(m0 + row16) * IN_F + kbase);

#pragma unroll
    for (int kk = 0; kk < 128; kk += 32) {
        float4 u0 = hp[kk / 4 + kgrp * 2];
        float4 u1 = hp[kk / 4 + kgrp * 2 + 1];
        bf16x8 af;
        af[0] = f2bf(u0.x); af[1] = f2bf(u0.y); af[2] = f2bf(u0.z); af[3] = f2bf(u0.w);
        af[4] = f2bf(u1.x); af[5] = f2bf(u1.y); af[6] = f2bf(u1.z); af[7] = f2bf(u1.w);
#pragma unroll
        for (int nt = 0; nt < 8; nt++) {
            bf16x8 bf_ = *(const bf16x8*)(WT + (size_t)(nt * 16 + row16) * IN_F + kbase + kk + kgrp * 8);
            acc[nt] = __builtin_amdgcn_mfma_f32_16x16x32_bf16(af, bf_, acc[nt], 0, 0, 0);
        }
    }

    __shared__ float red[4][16][132];
#pragma unroll
    for (int nt = 0; nt < 8; nt++)
#pragma unroll
        for (int r = 0; r < 4; r++)
            red[wave][kgrp * 4 + r][nt * 16 + row16] = acc[nt][r];
    __syncthreads();

    const int row = tid >> 4, seg = tid & 15;
    float v[8];
#pragma unroll
    for (int e = 0; e < 8; e++) {
        int c = seg * 8 + e;
        v[e] = red[0][row][c] + red[1][row][c] + red[2][row][c] + red[3][row][c];
    }
    float sp = 0.f, tp = 0.f;
#pragma unroll
    for (int e = 0; e < 8; e++) {
        sp += v[e] * a[seg * 8 + e];
        tp += v[e] * a[OUT_F + seg * 8 + e];
    }
    sp += __shfl_xor(sp, 1); tp += __shfl_xor(tp, 1);
    sp += __shfl_xor(sp, 2); tp += __shfl_xor(tp, 2);
    sp += __shfl_xor(sp, 4); tp += __shfl_xor(tp, 4);
    sp += __shfl_xor(sp, 8); tp += __shfl_xor(tp, 8);
    if (seg == 0) {
        sOut[m0 + row] = sp * LOG2E;
        tOut[m0 + row] = tp * LOG2E;
    }
#pragma unroll
    for (int e = 0; e < 8; e++)
        WhT[(size_t)(seg * 8 + e) * N + m0 + row] = f2bf(v[e]);
}

// ---------------------------------------------------------------- attn: fused adj stream + softmax-GEMM
// 1-D grid 1024; kb = blockIdx.x & 7 (XCD-pinned K-slice); 256 thr = 4 waves; wave = 16M x 128N x 1024K.
// adj loaded consumer-aligned at distance-2 supers; manual vmcnt(4)+s_barrier keeps adj in flight
// across barriers while draining the B stages (R7's vmcnt(0) failure mode avoided).
__global__ __launch_bounds__(256, 4) void attn(const int* __restrict__ adj,
                                               const short* __restrict__ WhT,
                                               const float* __restrict__ s,
                                               const float* __restrict__ t,
                                               unsigned short* __restrict__ num,
                                               float* __restrict__ lpart) {
    const int tid = threadIdx.x;
    const int wave = tid >> 6, lane = tid & 63;
    const int row16 = lane & 15, kgrp = lane >> 4;
    const int kb = blockIdx.x & 7;
    const int mb = blockIdx.x >> 3;
    const int m0 = mb * 64 + wave * 16;
    const int m  = m0 + row16;
    const int ks = kb * KC;

    __shared__ short Bs[2][2][128 * 32];   // 32 KB
    __shared__ float tl[KC];               // 4 KB

    for (int i = tid; i < KC; i += 256) tl[i] = t[ks + i];

    const float s_m = s[m];
    // lane's adj stream (consumer-aligned): int4 index sp*16 + d*8 + q from this base
    const i32x4* arow = (const i32x4*)(adj + (size_t)m * N + ks + kgrp * 8);

    auto stageB = [&](int sup, int par) {
        const int k0 = ks + sup * 64;
#pragma unroll
        for (int d = 0; d < 2; d++)
#pragma unroll
            for (int q = 0; q < 2; q++) {
                int nrow = wave * 32 + q * 16 + (lane >> 2);
                const short* g = WhT + (size_t)nrow * N + k0 + d * 32 + (lane & 3) * 8;
                load_lds16(g, &Bs[par][d][(wave * 32 + q * 16) * 32]);
            }
    };

    i32x4 G[2][4];                         // [parity][d*2+q], supers sp, sp+1 in flight
#pragma unroll
    for (int p = 0; p < 2; p++)
#pragma unroll
        for (int j = 0; j < 4; j++)
            G[p][j] = __builtin_nontemporal_load(arow + p * 16 + (j >> 1) * 8 + (j & 1));

    f32x4 acc[8] = {};
    float lsum = 0.f;

    stageB(0, 0);
    __syncthreads();                       // drains preloads + tl + B super 0

    auto super_body = [&](int sp, bool dostage, bool doadj) {
        const int par = sp & 1;
        if (dostage) stageB(sp + 1, par ^ 1);          // 8 global_load_lds
        // compress super sp (G[par] landed >=1.5 iters ago)
        unsigned mbyte[2];
#pragma unroll
        for (int d = 0; d < 2; d++) {
            i32x4 a0 = G[par][d * 2], a1 = G[par][d * 2 + 1];
            mbyte[d] = (a0.x > 0 ? 1u : 0u) | (a0.y > 0 ? 2u : 0u) |
                       (a0.z > 0 ? 4u : 0u) | (a0.w > 0 ? 8u : 0u) |
                       (a1.x > 0 ? 16u : 0u) | (a1.y > 0 ? 32u : 0u) |
                       (a1.z > 0 ? 64u : 0u) | (a1.w > 0 ? 128u : 0u);
        }
        if (doadj) {                                   // refill with super sp+2 (4 loads, newest in queue)
#pragma unroll
            for (int j = 0; j < 4; j++)
                G[par][j] = __builtin_nontemporal_load(arow + (sp + 2) * 16 + (j >> 1) * 8 + (j & 1));
        }
#pragma unroll
        for (int d = 0; d < 2; d++) {
            const int g = sp * 2 + d;
            const float* tp = tl + g * 32 + kgrp * 8;
            float4 tA = *(const float4*)tp;
            float4 tB = *(const float4*)(tp + 4);
            float tv[8] = { tA.x, tA.y, tA.z, tA.w, tB.x, tB.y, tB.z, tB.w };

            bf16x8 bfr[8];
            const short* base = &Bs[par][d][0];
#pragma unroll
            for (int ni = 0; ni < 8; ni++)
                bfr[ni] = *(const bf16x8*)(base + (ni * 16 + row16) * 32 + kgrp * 8);

            unsigned pu[8];
#pragma unroll
            for (int e = 0; e < 8; e++) {
                float x = s_m + tv[e];
                x = fmaxf(x, 0.2f * x);                    // leaky relu
                float p = exp2fast(x);                     // s,t pre-scaled by log2e
                unsigned u = __float_as_uint(p) & 0xFFFF0000u;
                u = ((mbyte[d] >> e) & 1u) ? u : 0u;
                lsum += __uint_as_float(u);                // consistent with numerator
                pu[e] = u;
            }
            bf16x8 af;
            unsigned* au = (unsigned*)&af;
#pragma unroll
            for (int q = 0; q < 4; q++) au[q] = (pu[2 * q] >> 16) | pu[2 * q + 1];
#pragma unroll
            for (int ni = 0; ni < 8; ni++)
                acc[ni] = __builtin_amdgcn_mfma_f32_16x16x32_bf16(af, bfr[ni], acc[ni], 0, 0, 0);
        }
    };

    for (int sp = 0; sp < 14; sp++) {
        super_body(sp, true, true);
        __builtin_amdgcn_s_waitcnt(0x0F74);   // vmcnt(4) expcnt(7) lgkmcnt(15): drain B stage, keep adj(sp+2)
        __builtin_amdgcn_s_barrier();
    }
    super_body(14, true, false);
    __builtin_amdgcn_s_waitcnt(0x0F70);       // vmcnt(0): nothing left to protect
    __builtin_amdgcn_s_barrier();
    super_body(15, false, false);

    // row sum across kgrp lanes
    {
        float v = lsum;
        v += __shfl_xor(v, 16);
        v += __shfl_xor(v, 32);
        if (kgrp == 0) lpart[(size_t)kb * N + m] = v;
    }

    // partial numerator, bf16: C layout row = kgrp*4+r (m within 16), col = ni*16+row16
    unsigned short* np_ = num + ((size_t)kb * N + m0) * OUT_F;
#pragma unroll
    for (int ni = 0; ni < 8; ni++) {
        int n = ni * 16 + row16;
#pragma unroll
        for (int r = 0; r < 4; r++)
            np_[(size_t)(kgrp * 4 + r) * OUT_F + n] = (unsigned short)f2bf(acc[ni][r]);
    }
}

// ---------------------------------------------------------------- finalize: reduce bf16 splits, /l, +rnd, elu
__global__ __launch_bounds__(256) void finalize(const unsigned short* __restrict__ num,
                                                const float* __restrict__ lpart,
                                                const float* __restrict__ rnd,
                                                float* __restrict__ out) {
    int idx = blockIdx.x * 256 + threadIdx.x;   // one thread = 8 outputs
    int m = idx >> 4;
    int c = (idx & 15) * 8;
    size_t g = (size_t)m * OUT_F + c;

    float nm[8] = {};
#pragma unroll
    for (int bk = 0; bk < SPLITK; bk++) {
        u16x8 v = *(const u16x8*)(num + (size_t)bk * N * OUT_F + g);
#pragma unroll
        for (int e = 0; e < 8; e++) nm[e] += __uint_as_float((unsigned)v[e] << 16);
    }
    float l = 0.f;
#pragma unroll
    for (int bk = 0; bk < SPLITK; bk++) l += lpart[(size_t)bk * N + m];
    float inv = 1.f / fmaxf(l, 1e-30f);

    float4 r0 = *(const float4*)(rnd + g);
    float4 r1 = *(const float4*)(rnd + g + 4);
    float rv[8] = { r0.x, r0.y, r0.z, r0.w, r1.x, r1.y, r1.z, r1.w };
    float ov[8];
#pragma unroll
    for (int e = 0; e < 8; e++) {
        float x = (nm[e] * inv + rv[e]) * 1e-5f;
        ov[e] = x > 0.f ? x : __expf(x) - 1.f;
    }
    *(float4*)(out + g)     = make_float4(ov[0], ov[1], ov[2], ov[3]);
    *(float4*)(out + g + 4) = make_float4(ov[4], ov[5], ov[6], ov[7]);
}

extern "C" void kernel_launch(void* const* d_in, const int* in_sizes, int n_in,
                              void* d_out, int out_size, void* d_ws, size_t ws_size,
                              hipStream_t stream) {
    const float* h   = (const float*)d_in[0];
    const int*   adj = (const int*)d_in[1];
    const float* W   = (const float*)d_in[2];
    const float* a   = (const float*)d_in[3];
    const float* rnd = (const float*)d_in[4];
    float* out = (float*)d_out;

    char* w = (char*)d_ws;
    short* WT    = (short*)(w);                            // 131072
    short* WhT   = (short*)(w + 131072);                   // 2097152 -> 2228224
    float* sv    = (float*)(w + 2228224);                  // 32768   -> 2260992
    float* tv    = (float*)(w + 2260992);                  // 32768   -> 2293760
    float* lpart = (float*)(w + 2293760);                  // 262144  -> 2555904
    unsigned short* num = (unsigned short*)(w + 2555904);  // 16777216 -> 19333120 (~19 MB)

    conv_W  <<<256, 256, 0, stream>>>(W, WT);
    gemm_hW <<<512, 256, 0, stream>>>(h, WT, a, WhT, sv, tv);
    attn    <<<1024, 256, 0, stream>>>(adj, WhT, sv, tv, num, lpart);
    finalize<<<(N * OUT_F / 8) / 256, 256, 0, stream>>>(num, lpart, rnd, out);
}